// Round 7
// baseline (41619.412 us; speedup 1.0000x reference)
//
#include <hip/hip_runtime.h>
#include <hip/hip_bf16.h>

#define BATCH 16384
#define TSTEPS 101
#define HDIM 512
#define GDIM 2048
#define ROWS 64      // batch rows per chain block
#define NBLK 256

typedef __attribute__((ext_vector_type(8))) short s16x8;
typedef __attribute__((ext_vector_type(16))) float f32x16;
typedef __attribute__((ext_vector_type(4))) float f32x4;

__device__ __forceinline__ float sigm(float x){ return 1.0f/(1.0f + __expf(-x)); }
__device__ __forceinline__ float tanhx(float x){ float e=__expf(2.0f*x); return 1.0f - 2.0f/(e+1.0f); }

__device__ __forceinline__ void gload16(const void* g, void* l){
  __builtin_amdgcn_global_load_lds((const __attribute__((address_space(1))) unsigned int*)g,
                                   (__attribute__((address_space(3))) unsigned int*)l, 16, 0, 0);
}

// One block = 64 batch rows, ALL 101 timesteps (recurrence is row-local -> blocks independent).
// h(t): LDS 64KB bf16, XOR-swizzled (oct ^= row&7), rewritten in place each step.
// c: VGPRs (fp32, 64/thread). W: streamed via 2x32KB LDS double-buffer, counted vmcnt(4).
// Wave w owns output hcols [w*64, w*64+64) x 4 gates, split in 2 passes of 32 hcols.
// MFMA 32x32x16; gates live in the accumulator dim -> cell update is lane-local.
__global__ __launch_bounds__(512, 2) void lstm_chain(
    const float* __restrict__ bx,
    const float* __restrict__ Wih,
    const float* __restrict__ bcomb,
    const __hip_bfloat16* __restrict__ wbf,
    __hip_bfloat16* __restrict__ hT)
{
  __shared__ short sH[ROWS*HDIM];    // 64KB h(t)
  __shared__ short sW[2*16384];      // 2 x (1024 W-rows x 16 k) = 64KB

  const int tid = threadIdx.x;
  const int l = tid & 63, w = tid >> 6;
  const int lo = l & 31, hi = l >> 5;
  const int x7 = lo & 7;
  const int r0 = blockIdx.x * ROWS;

  // zero h(0)
  {
    int4 z = {0,0,0,0};
    #pragma unroll
    for (int i = 0; i < 8; ++i) *(int4*)&sH[(i*512 + tid)*8] = z;
  }

  // W staging: 2048 chunks of 16B per k-tile; 4/thread. LDS linear (wave-linear dst),
  // source carries the swizzle: phys slot sl holds k-octet (sl ^ (ridx&1)).
  const __hip_bfloat16* wsrc[4]; int wdst[4];
  #pragma unroll
  for (int i = 0; i < 4; ++i){
    int c = i*512 + tid;
    int ridx = c >> 1, sl = c & 1;
    int g = ridx >> 8, wv = (ridx >> 5) & 7, cc = ridx & 31;
    int wrow = g*HDIM + wv*64 + cc;          // + p*32 rows added at stage time
    wsrc[i] = wbf + (size_t)wrow*HDIM + ((sl ^ (ridx & 1)) << 3);
    wdst[i] = c*8;
  }
  // B-frag read bases (bytes into sW): ridx = g*256 + w*32 + lo, slot = hi ^ (lo&1)
  int pbb[4];
  #pragma unroll
  for (int g = 0; g < 4; ++g)
    pbb[g] = ((g*256 + w*32 + lo) << 5) + ((hi ^ (lo & 1)) << 4);
  const int rowb0 = lo << 10, rowb1 = (32 + lo) << 10;

  f32x16 creg[2][2] = {};     // c state [pass][m]
  unsigned hp[16];            // pass-0 pending h (bf16 pairs)

  __syncthreads();

  const float* bxb = bx + (size_t)r0*TSTEPS*4;

#define STAGE(BUF, P, KT) do{                                          \
    const int so_ = (P)*16384 + (KT)*16;                               \
    gload16(wsrc[0] + so_, &sW[((BUF)<<14) + wdst[0]]);                \
    gload16(wsrc[1] + so_, &sW[((BUF)<<14) + wdst[1]]);                \
    gload16(wsrc[2] + so_, &sW[((BUF)<<14) + wdst[2]]);                \
    gload16(wsrc[3] + so_, &sW[((BUF)<<14) + wdst[3]]);                \
  }while(0)

  for (int t = 0; t < TSTEPS; ++t){
    if (t > 0) STAGE(0, 0, 0);
    #pragma unroll
    for (int p = 0; p < 2; ++p){
      f32x16 acc[4][2] = {};
      if (t > 0){
        for (int kt = 0; kt < 32; ++kt){
          const int rd = p*32 + kt;
          __builtin_amdgcn_s_barrier();          // safe to overwrite buf[(rd+1)&1]
          if (p == 0 || kt < 31){
            STAGE((rd+1)&1, (rd+1)>>5, (rd+1)&31);
            asm volatile("s_waitcnt vmcnt(4)" ::: "memory");  // STAGE(rd) landed
          } else {
            asm volatile("s_waitcnt vmcnt(0)" ::: "memory");
          }
          __builtin_amdgcn_s_barrier();
          __builtin_amdgcn_sched_barrier(0);
          const int aoff = ((kt*2 + hi) ^ x7) << 4;
          s16x8 av0 = *(const s16x8*)((const char*)sH + rowb0 + aoff);
          s16x8 av1 = *(const s16x8*)((const char*)sH + rowb1 + aoff);
          const char* wb = (const char*)sW + ((rd & 1) << 15);
          #pragma unroll
          for (int g = 0; g < 4; ++g){
            s16x8 bv = *(const s16x8*)(wb + pbb[g]);
            acc[g][0] = __builtin_amdgcn_mfma_f32_32x32x16_bf16(av0, bv, acc[g][0], 0, 0, 0);
            acc[g][1] = __builtin_amdgcn_mfma_f32_32x32x16_bf16(av1, bv, acc[g][1], 0, 0, 0);
          }
        }
      }
      // ---- epilogue pass p ----
      if (p == 1) __builtin_amdgcn_s_barrier();  // all waves done reading h(t)
      const int colg = w*64 + p*32 + lo;
      float4 wv4[4]; float bc4[4];
      #pragma unroll
      for (int g = 0; g < 4; ++g){
        wv4[g] = *(const float4*)(Wih + (size_t)(g*HDIM + colg)*4);
        bc4[g] = bcomb[g*HDIM + colg];
      }
      const int cb = w*8 + (lo >> 3) + p*4;      // col-octet of this pass
      const int cb0 = w*8 + (lo >> 3);           // col-octet of pass 0 (pending)
      #pragma unroll
      for (int m = 0; m < 2; ++m){
        #pragma unroll
        for (int q = 0; q < 4; ++q){
          #pragma unroll
          for (int i2 = 0; i2 < 4; ++i2){
            const int reg = q*4 + i2;
            const int lr = m*32 + q*8 + hi*4 + i2;
            const float4 xv = *(const float4*)(bxb + (size_t)lr*TSTEPS*4 + (size_t)t*4);
            float pi = acc[0][m][reg] + bc4[0] + xv.x*wv4[0].x + xv.y*wv4[0].y + xv.z*wv4[0].z + xv.w*wv4[0].w;
            float pf = acc[1][m][reg] + bc4[1] + xv.x*wv4[1].x + xv.y*wv4[1].y + xv.z*wv4[1].z + xv.w*wv4[1].w;
            float pg = acc[2][m][reg] + bc4[2] + xv.x*wv4[2].x + xv.y*wv4[2].y + xv.z*wv4[2].z + xv.w*wv4[2].w;
            float po = acc[3][m][reg] + bc4[3] + xv.x*wv4[3].x + xv.y*wv4[3].y + xv.z*wv4[3].z + xv.w*wv4[3].w;
            float iv = sigm(pi), fv = sigm(pf), gv = tanhx(pg), ov = sigm(po);
            float cn = fv*creg[p][m][reg] + iv*gv;
            creg[p][m][reg] = cn;
            __hip_bfloat16 hv = __float2bfloat16(ov*tanhx(cn));
            unsigned hb = *reinterpret_cast<unsigned short*>(&hv);
            if (p == 0){
              const int hidx = m*8 + q*2 + (i2 >> 1);
              if ((i2 & 1) == 0) hp[hidx] = hb;
              else               hp[hidx] |= (hb << 16);
            } else {
              // own h value
              sH[((lr << 10) + ((cb ^ (lr & 7)) << 4) + ((lo & 7) << 1)) >> 1] = (short)hb;
              // pass-0 pending h value for same (m,q,i2)
              const int hidx = m*8 + q*2 + (i2 >> 1);
              unsigned u = hp[hidx];
              unsigned hb0v = (i2 & 1) ? (u >> 16) : (u & 0xffffu);
              sH[((lr << 10) + ((cb0 ^ (lr & 7)) << 4) + ((lo & 7) << 1)) >> 1] = (short)hb0v;
            }
          }
        }
      }
      if (p == 1) __syncthreads();   // h(t+1) visible before next step's GEMM
    }
  }
#undef STAGE

  // final h -> global (unswizzle, coalesced 16B chunks)
  #pragma unroll
  for (int i = 0; i < 8; ++i){
    int cc = i*512 + tid;
    int row = cc >> 6, oct = cc & 63;
    s16x8 v = *(const s16x8*)((const char*)sH + (row << 10) + ((oct ^ (row & 7)) << 4));
    *(s16x8*)(hT + (size_t)(r0 + row)*HDIM + oct*8) = v;
  }
}

__global__ void prep(const float* __restrict__ Whh, const float* __restrict__ W1,
                     const float* __restrict__ bih, const float* __restrict__ bhh,
                     __hip_bfloat16* __restrict__ wbf, __hip_bfloat16* __restrict__ w1bf,
                     float* __restrict__ bcomb){
  int i = blockIdx.x*256 + threadIdx.x;
  if (i < GDIM*HDIM) wbf[i] = __float2bfloat16(Whh[i]);
  if (i < HDIM*HDIM) w1bf[i] = __float2bfloat16(W1[i]);
  if (i < GDIM) bcomb[i] = bih[i] + bhh[i];
}

// x = relu(hT @ W1^T + b1), bf16 MFMA, fp32 out. Block 128x128, wave 32x128.
__global__ __launch_bounds__(256) void mlp1(const __hip_bfloat16* __restrict__ hT,
                                            const __hip_bfloat16* __restrict__ w1bf,
                                            const float* __restrict__ b1, float* __restrict__ xout){
  __shared__ short sA[128*64];
  __shared__ short sB[128*64];
  const int tid = threadIdx.x;
  const int l = tid & 63, w = tid >> 6;
  const int lr = l & 15, lk = l >> 4;
  const int r0 = blockIdx.x * 128, c0 = blockIdx.y * 128;

  f32x4 acc[2][8] = {};
  for (int k0 = 0; k0 < HDIM; k0 += 64){
    __syncthreads();
    #pragma unroll
    for (int i = 0; i < 4; ++i){
      int cch = i*256 + tid;
      int row = cch >> 3, kc = cch & 7;
      int kcs = kc ^ (row & 7);
      gload16(hT + (size_t)(r0 + row)*HDIM + k0 + kcs*8, &sA[cch*8]);
    }
    #pragma unroll
    for (int i = 0; i < 4; ++i){
      int cch = i*256 + tid;
      int row = cch >> 3, kc = cch & 7;
      int kcs = kc ^ (row & 7);
      gload16(w1bf + (size_t)(c0 + row)*HDIM + k0 + kcs*8, &sB[cch*8]);
    }
    __syncthreads();
    #pragma unroll
    for (int kk = 0; kk < 2; ++kk){
      s16x8 av[2];
      #pragma unroll
      for (int m = 0; m < 2; ++m){
        int row = w*32 + m*16 + lr;
        int slot = row*8 + ((kk*4 + lk) ^ (row & 7));
        av[m] = *(const s16x8*)&sA[slot*8];
      }
      #pragma unroll
      for (int n = 0; n < 8; ++n){
        int rB = n*16 + lr;
        int slot = rB*8 + ((kk*4 + lk) ^ (rB & 7));
        s16x8 bv = *(const s16x8*)&sB[slot*8];
        #pragma unroll
        for (int m = 0; m < 2; ++m)
          acc[m][n] = __builtin_amdgcn_mfma_f32_16x16x32_bf16(av[m], bv, acc[m][n], 0, 0, 0);
      }
    }
  }
  #pragma unroll
  for (int m = 0; m < 2; ++m){
    #pragma unroll
    for (int rg = 0; rg < 4; ++rg){
      int r = r0 + w*32 + m*16 + lk*4 + rg;
      #pragma unroll
      for (int n = 0; n < 8; ++n){
        int c = c0 + n*16 + lr;
        float v = acc[m][n][rg] + b1[c];
        xout[(size_t)r*HDIM + c] = v > 0.f ? v : 0.f;
      }
    }
  }
}

// out[b] = x[b,:] . W2[0:512] + a[b]*W2[512] + b2 ; one wave per row
__global__ __launch_bounds__(256) void mlp2(const float* __restrict__ x, const float* __restrict__ a,
                                            const float* __restrict__ W2, const float* __restrict__ b2,
                                            float* __restrict__ out){
  const int wi = threadIdx.x >> 6, l = threadIdx.x & 63;
  const int b = blockIdx.x*4 + wi;
  const float* xr = x + (size_t)b*HDIM;
  float4 v0 = *(const float4*)(xr + l*8);
  float4 v1 = *(const float4*)(xr + l*8 + 4);
  float4 w0 = *(const float4*)(W2 + l*8);
  float4 w1 = *(const float4*)(W2 + l*8 + 4);
  float s = v0.x*w0.x + v0.y*w0.y + v0.z*w0.z + v0.w*w0.w
          + v1.x*w1.x + v1.y*w1.y + v1.z*w1.z + v1.w*w1.w;
  #pragma unroll
  for (int off = 32; off > 0; off >>= 1) s += __shfl_down(s, off);
  if (l == 0) out[b] = s + a[b]*W2[HDIM] + b2[0];
}

extern "C" void kernel_launch(void* const* d_in, const int* in_sizes, int n_in,
                              void* d_out, int out_size, void* d_ws, size_t ws_size,
                              hipStream_t stream){
  const float* bx  = (const float*)d_in[0];
  const float* ba  = (const float*)d_in[1];
  const float* Wih = (const float*)d_in[2];
  const float* Whh = (const float*)d_in[3];
  const float* bih = (const float*)d_in[4];
  const float* bhh = (const float*)d_in[5];
  const float* W1  = (const float*)d_in[6];
  const float* b1  = (const float*)d_in[7];
  const float* W2  = (const float*)d_in[8];
  const float* b2  = (const float*)d_in[9];
  float* out = (float*)d_out;

  char* ws = (char*)d_ws;
  __hip_bfloat16* wbf   = (__hip_bfloat16*)(ws);              // 2 MB
  __hip_bfloat16* w1bf  = (__hip_bfloat16*)(ws + 2097152);    // 512 KB
  float*          bcomb = (float*)(ws + 2621440);             // 8 KB
  __hip_bfloat16* hTb   = (__hip_bfloat16*)(ws + 2629632);    // 16 MB (final h)
  float*          xmlp  = (float*)(ws + 19406848);            // 32 MB (mlp intermediate)

  prep<<<4096, 256, 0, stream>>>(Whh, W1, bih, bhh, wbf, w1bf, bcomb);

  lstm_chain<<<NBLK, 512, 0, stream>>>(bx, Wih, bcomb, wbf, hTb);

  mlp1<<<dim3(128, 4), 256, 0, stream>>>(hTb, w1bf, b1, xmlp);
  mlp2<<<4096, 256, 0, stream>>>(xmlp, ba, W2, b2, out);
}

// Round 8
// 6597.229 us; speedup vs baseline: 6.3086x; 6.3086x over previous
//
#include <hip/hip_runtime.h>
#include <hip/hip_bf16.h>

#define BATCH 16384
#define TSTEPS 101
#define HDIM 512
#define GDIM 2048  // 4*H

typedef __attribute__((ext_vector_type(8))) short s16x8;
typedef __attribute__((ext_vector_type(4))) float f32x4;

__device__ __forceinline__ float sigm(float x){ return 1.0f/(1.0f + __expf(-x)); }
__device__ __forceinline__ float tanhx(float x){ float e=__expf(2.0f*x); return 1.0f - 2.0f/(e+1.0f); }

__device__ __forceinline__ void gload16(const void* g, void* l){
  __builtin_amdgcn_global_load_lds((const __attribute__((address_space(1))) unsigned int*)g,
                                   (__attribute__((address_space(3))) unsigned int*)l, 16, 0, 0);
}

// gates = hin @ W_hh^T (+ x_t @ W_ih^T + b), then LSTM cell update.
// 1024 blocks XCD-chunked: 64 row-panels (256 rows) x 16 col-blocks (32 hcols x 4 gates).
// 256 threads = 4 waves; wave = 128 rows x 64 gatecols (4 gates x 16 hcols) ->
// per K-tile per wave: 24 ds_read_b128 vs 64 MFMA (balanced), vs R2's 20:32.
// BK=64, single-buffered 48KB LDS, XOR swizzle (2-way = free), 2 syncs/K-tile.
__global__ __launch_bounds__(256, 2) void lstm_step(
    const __hip_bfloat16* __restrict__ hin,
    __hip_bfloat16* __restrict__ hout,
    float* __restrict__ cbuf,
    const float* __restrict__ bx,
    const float* __restrict__ Wih,
    const float* __restrict__ bcomb,
    const __hip_bfloat16* __restrict__ wbf,
    int t, int skipmm)
{
  __shared__ short sA[256*64];   // 256 batch rows x 64 k
  __shared__ short sB[128*64];   // (4 gates x 32 hcols) x 64 k
  const int tid = threadIdx.x;
  const int l = tid & 63, w = tid >> 6;
  const int lr = l & 15, lk = l >> 4;
  const int wr = w >> 1, wc = w & 1;   // row-half / hcol-half of the block tile

  const int orig = blockIdx.x;
  const int swz = (orig & 7)*128 + (orig >> 3);   // XCD-chunked, bijective (1024%8==0)
  const int panel = swz >> 4;            // 0..63 : 256-row panel
  const int cb    = swz & 15;            // 0..15 : 32-hcol block

  f32x4 acc[4][8] = {};                  // [gate][m]  (128 VGPR)

  if (!skipmm){
    // staging: A 2048 + B 1024 chunks of 16B; 8+4 per thread. LDS linear, source pre-swizzled.
    const __hip_bfloat16* asrc[8]; int adst[8];
    #pragma unroll
    for (int i = 0; i < 8; ++i){
      int c = i*256 + tid;
      int row = c >> 3, s = c & 7;
      int kc = s ^ (row & 7);
      asrc[i] = hin + (size_t)(panel*256 + row)*HDIM + kc*8;
      adst[i] = c*8;
    }
    const __hip_bfloat16* bsrc[4]; int bdst[4];
    #pragma unroll
    for (int i = 0; i < 4; ++i){
      int c = i*256 + tid;
      int row = c >> 3, s = c & 7;
      int kc = s ^ (row & 7);
      int g = row >> 5, hcw = row & 31;
      bsrc[i] = wbf + (size_t)(g*HDIM + cb*32 + hcw)*HDIM + kc*8;
      bdst[i] = c*8;
    }

    for (int kt = 0; kt < 8; ++kt){
      const int k0 = kt*64;
      __syncthreads();
      #pragma unroll
      for (int i = 0; i < 8; ++i) gload16(asrc[i] + k0, &sA[adst[i]]);
      #pragma unroll
      for (int i = 0; i < 4; ++i) gload16(bsrc[i] + k0, &sB[bdst[i]]);
      __syncthreads();
      #pragma unroll
      for (int kk = 0; kk < 2; ++kk){
        s16x8 av[8];
        #pragma unroll
        for (int m = 0; m < 8; ++m){
          int row = wr*128 + m*16 + lr;
          int slot = row*8 + ((kk*4 + lk) ^ (row & 7));
          av[m] = *(const s16x8*)&sA[slot*8];
        }
        #pragma unroll
        for (int g = 0; g < 4; ++g){
          int rB = g*32 + wc*16 + lr;
          int slot = rB*8 + ((kk*4 + lk) ^ (rB & 7));
          s16x8 bv = *(const s16x8*)&sB[slot*8];
          #pragma unroll
          for (int m = 0; m < 8; ++m)
            acc[g][m] = __builtin_amdgcn_mfma_f32_16x16x32_bf16(av[m], bv, acc[g][m], 0, 0, 0);
        }
      }
    }
  }

  // Epilogue: add x-projection + bias, apply cell update.
  // C/D mapping (m89): col = lane&15, row = (lane>>4)*4 + reg.
  const int colg = cb*32 + wc*16 + lr;
  float4 wv[4]; float bc4[4];
  #pragma unroll
  for (int g = 0; g < 4; ++g){
    int gc = g*HDIM + colg;
    wv[g]  = *(const float4*)(Wih + (size_t)gc*4);
    bc4[g] = bcomb[gc];
  }
  #pragma unroll
  for (int m = 0; m < 8; ++m){
    #pragma unroll
    for (int rg = 0; rg < 4; ++rg){
      int r = panel*256 + wr*128 + m*16 + lk*4 + rg;
      float4 xv = *(const float4*)(bx + ((size_t)r*TSTEPS + t)*4);
      float pi = acc[0][m][rg] + bc4[0] + xv.x*wv[0].x + xv.y*wv[0].y + xv.z*wv[0].z + xv.w*wv[0].w;
      float pf = acc[1][m][rg] + bc4[1] + xv.x*wv[1].x + xv.y*wv[1].y + xv.z*wv[1].z + xv.w*wv[1].w;
      float pg = acc[2][m][rg] + bc4[2] + xv.x*wv[2].x + xv.y*wv[2].y + xv.z*wv[2].z + xv.w*wv[2].w;
      float po = acc[3][m][rg] + bc4[3] + xv.x*wv[3].x + xv.y*wv[3].y + xv.z*wv[3].z + xv.w*wv[3].w;
      float iv = sigm(pi), fv = sigm(pf), gv = tanhx(pg), ov = sigm(po);
      size_t idx = (size_t)r*HDIM + colg;
      float cold = skipmm ? 0.f : cbuf[idx];   // t=0: c0 = 0 (no memset needed)
      float cn = fv*cold + iv*gv;
      cbuf[idx] = cn;
      hout[idx] = __float2bfloat16(ov*tanhx(cn));
    }
  }
}

__global__ void prep(const float* __restrict__ Whh, const float* __restrict__ W1,
                     const float* __restrict__ bih, const float* __restrict__ bhh,
                     __hip_bfloat16* __restrict__ wbf, __hip_bfloat16* __restrict__ w1bf,
                     float* __restrict__ bcomb){
  int i = blockIdx.x*256 + threadIdx.x;
  if (i < GDIM*HDIM) wbf[i] = __float2bfloat16(Whh[i]);
  if (i < HDIM*HDIM) w1bf[i] = __float2bfloat16(W1[i]);
  if (i < GDIM) bcomb[i] = bih[i] + bhh[i];
}

// x = relu(hT @ W1^T + b1), bf16 MFMA, fp32 out. Block 128x128, wave 32x128.
__global__ __launch_bounds__(256) void mlp1(const __hip_bfloat16* __restrict__ hT,
                                            const __hip_bfloat16* __restrict__ w1bf,
                                            const float* __restrict__ b1, float* __restrict__ xout){
  __shared__ short sA[128*64];
  __shared__ short sB[128*64];
  const int tid = threadIdx.x;
  const int l = tid & 63, w = tid >> 6;
  const int lr = l & 15, lk = l >> 4;
  const int r0 = blockIdx.x * 128, c0 = blockIdx.y * 128;

  f32x4 acc[2][8] = {};
  for (int k0 = 0; k0 < HDIM; k0 += 64){
    __syncthreads();
    #pragma unroll
    for (int i = 0; i < 4; ++i){
      int cch = i*256 + tid;
      int row = cch >> 3, kc = cch & 7;
      int kcs = kc ^ (row & 7);
      gload16(hT + (size_t)(r0 + row)*HDIM + k0 + kcs*8, &sA[cch*8]);
    }
    #pragma unroll
    for (int i = 0; i < 4; ++i){
      int cch = i*256 + tid;
      int row = cch >> 3, kc = cch & 7;
      int kcs = kc ^ (row & 7);
      gload16(w1bf + (size_t)(c0 + row)*HDIM + k0 + kcs*8, &sB[cch*8]);
    }
    __syncthreads();
    #pragma unroll
    for (int kk = 0; kk < 2; ++kk){
      s16x8 av[2];
      #pragma unroll
      for (int m = 0; m < 2; ++m){
        int row = w*32 + m*16 + lr;
        int slot = row*8 + ((kk*4 + lk) ^ (row & 7));
        av[m] = *(const s16x8*)&sA[slot*8];
      }
      #pragma unroll
      for (int n = 0; n < 8; ++n){
        int rB = n*16 + lr;
        int slot = rB*8 + ((kk*4 + lk) ^ (rB & 7));
        s16x8 bv = *(const s16x8*)&sB[slot*8];
        #pragma unroll
        for (int m = 0; m < 2; ++m)
          acc[m][n] = __builtin_amdgcn_mfma_f32_16x16x32_bf16(av[m], bv, acc[m][n], 0, 0, 0);
      }
    }
  }
  #pragma unroll
  for (int m = 0; m < 2; ++m){
    #pragma unroll
    for (int rg = 0; rg < 4; ++rg){
      int r = r0 + w*32 + m*16 + lk*4 + rg;
      #pragma unroll
      for (int n = 0; n < 8; ++n){
        int c = c0 + n*16 + lr;
        float v = acc[m][n][rg] + b1[c];
        xout[(size_t)r*HDIM + c] = v > 0.f ? v : 0.f;
      }
    }
  }
}

// out[b] = x[b,:] . W2[0:512] + a[b]*W2[512] + b2 ; one wave per row
__global__ __launch_bounds__(256) void mlp2(const float* __restrict__ x, const float* __restrict__ a,
                                            const float* __restrict__ W2, const float* __restrict__ b2,
                                            float* __restrict__ out){
  const int wi = threadIdx.x >> 6, l = threadIdx.x & 63;
  const int b = blockIdx.x*4 + wi;
  const float* xr = x + (size_t)b*HDIM;
  float4 v0 = *(const float4*)(xr + l*8);
  float4 v1 = *(const float4*)(xr + l*8 + 4);
  float4 w0 = *(const float4*)(W2 + l*8);
  float4 w1 = *(const float4*)(W2 + l*8 + 4);
  float s = v0.x*w0.x + v0.y*w0.y + v0.z*w0.z + v0.w*w0.w
          + v1.x*w1.x + v1.y*w1.y + v1.z*w1.z + v1.w*w1.w;
  #pragma unroll
  for (int off = 32; off > 0; off >>= 1) s += __shfl_down(s, off);
  if (l == 0) out[b] = s + a[b]*W2[HDIM] + b2[0];
}

extern "C" void kernel_launch(void* const* d_in, const int* in_sizes, int n_in,
                              void* d_out, int out_size, void* d_ws, size_t ws_size,
                              hipStream_t stream){
  const float* bx  = (const float*)d_in[0];
  const float* ba  = (const float*)d_in[1];
  const float* Wih = (const float*)d_in[2];
  const float* Whh = (const float*)d_in[3];
  const float* bih = (const float*)d_in[4];
  const float* bhh = (const float*)d_in[5];
  const float* W1  = (const float*)d_in[6];
  const float* b1  = (const float*)d_in[7];
  const float* W2  = (const float*)d_in[8];
  const float* b2  = (const float*)d_in[9];
  float* out = (float*)d_out;

  char* ws = (char*)d_ws;
  __hip_bfloat16* wbf   = (__hip_bfloat16*)(ws);              // 2 MB
  __hip_bfloat16* w1bf  = (__hip_bfloat16*)(ws + 2097152);    // 512 KB
  float*          bcomb = (float*)(ws + 2621440);             // 8 KB
  __hip_bfloat16* hb0   = (__hip_bfloat16*)(ws + 2629632);    // 16 MB
  __hip_bfloat16* hb1   = (__hip_bfloat16*)(ws + 19406848);   // 16 MB
  float*          cbuf  = (float*)(ws + 36184064);            // 32 MB (end ~66.5 MB)
  float*          xmlp  = cbuf;  // c dead after last step; reuse for MLP activations

  prep<<<4096, 256, 0, stream>>>(Whh, W1, bih, bhh, wbf, w1bf, bcomb);

  for (int t = 0; t < TSTEPS; ++t){
    const __hip_bfloat16* hin = (t & 1) ? hb1 : hb0;
    __hip_bfloat16*      hout = (t & 1) ? hb0 : hb1;
    lstm_step<<<1024, 256, 0, stream>>>(hin, hout, cbuf, bx, Wih, bcomb, wbf,
                                        t, (t == 0) ? 1 : 0);
  }
  // t=100 wrote hout = hb1
  mlp1<<<dim3(128, 4), 256, 0, stream>>>(hb1, w1bf, b1, xmlp);
  mlp2<<<4096, 256, 0, stream>>>(xmlp, ba, W2, b2, out);
}